// Round 10
// baseline (381.833 us; speedup 1.0000x reference)
//
#include <hip/hip_runtime.h>
#include <cstddef>

// SPDRectified: out = U clamp(S,eps) U^T for 16384 symmetric 64x64 fp32
// matrices via matrix-sign Newton-Schulz, one wave per matrix, bf16 matrix
// cores, 2-word hi/lo split (3-term products, fp32 accum).
//
// Round-10 = round-9 VERBATIM (378 us, absmax at the bf16-output floor) +
// pseudo-random per-block s_sleep stagger.
//   Evidence: r4 1-wave/SIMD MfmaUtil+VALUBusy = 45+55 = 100% (a lone wave
//   always keeps one pipe busy); r5 2-wave = 48+59 = 107% (second wave added
//   ~nothing) although m114 shows MFMA/VALU co-issue fine from different
//   waves. Diagnosis: identical streams launched together PHASE-LOCK --
//   both waves burst MFMA together (2x contention), then conv together.
//   Fix: hash(blockIdx)>>26 in [0,63] sleeps of ~64cyc = 0..4k cycle offset
//   (~ one product+conv period), pairing-agnostic. Mean cost ~2k cyc (~3%).
// Tripwires: absmax must stay exactly 0.03125; WRITE_SIZE == 262144 KB.
// Falsification: neutral dur => phase-lock theory dead (within-wave deps
// are the wall) -> next: 2-term products or roofline call.

#define QA 3.4445f
#define QB (-4.7750f)
#define QC 2.0315f
#define BETA    1.1938624f      // QC^(1/4)
#define C0COEF  (-3.3501551f)   // QB / sqrt(QC)
#define CWCOEF  (-0.3508013f)   // -0.5 / sqrt(QC)
#define CMCOEF  (0.4188090f)    // 0.5 / BETA
#define INVBETA (0.8376177f)    // 1 / BETA

using bf16x8 = __attribute__((ext_vector_type(8))) __bf16;
using f32x16 = __attribute__((ext_vector_type(16))) float;
using u32x4  = __attribute__((ext_vector_type(4))) unsigned int;
using u32x2  = __attribute__((ext_vector_type(2))) unsigned int;

__device__ __forceinline__ bf16x8 asbf(u32x4 v) { return __builtin_bit_cast(bf16x8, v); }

// Pack two f32 -> dword of 2 bf16 (RNE) + dword of 2 bf16 residuals.
__device__ __forceinline__ void split2(float x0, float x1, unsigned& h, unsigned& l) {
    unsigned hh, ll;
    asm("v_cvt_pk_bf16_f32 %0, %1, %2" : "=v"(hh) : "v"(x0), "v"(x1));
    const float e0 = x0 - __uint_as_float(hh << 16);
    const float e1 = x1 - __uint_as_float(hh & 0xFFFF0000u);
    asm("v_cvt_pk_bf16_f32 %0, %1, %2" : "=v"(ll) : "v"(e0), "v"(e1));
    h = hh; l = ll;
}

#define MFMA_(A, B, C) __builtin_amdgcn_mfma_f32_32x32x16_bf16(asbf(A), asbf(B), C, 0, 0, 0)

// 3-term product accumulating into pre-initialized acc (C-operand seeding).
__device__ __forceinline__ void mm12c(const u32x4 (&Ah)[2][4], const u32x4 (&Al)[2][4],
                                      const u32x4 (&Bh)[2][4], const u32x4 (&Bl)[2][4],
                                      f32x16 (&acc)[4]) {
    __builtin_amdgcn_s_setprio(1);
#pragma unroll
    for (int q = 0; q < 4; ++q) {
        acc[0] = MFMA_(Ah[0][q], Bh[0][q], acc[0]);
        acc[1] = MFMA_(Ah[0][q], Bh[1][q], acc[1]);
        acc[2] = MFMA_(Ah[1][q], Bh[0][q], acc[2]);
        acc[3] = MFMA_(Ah[1][q], Bh[1][q], acc[3]);
    }
#pragma unroll
    for (int q = 0; q < 4; ++q) {
        acc[0] = MFMA_(Ah[0][q], Bl[0][q], acc[0]);
        acc[1] = MFMA_(Ah[0][q], Bl[1][q], acc[1]);
        acc[2] = MFMA_(Ah[1][q], Bl[0][q], acc[2]);
        acc[3] = MFMA_(Ah[1][q], Bl[1][q], acc[3]);
    }
#pragma unroll
    for (int q = 0; q < 4; ++q) {
        acc[0] = MFMA_(Al[0][q], Bh[0][q], acc[0]);
        acc[1] = MFMA_(Al[0][q], Bh[1][q], acc[1]);
        acc[2] = MFMA_(Al[1][q], Bh[0][q], acc[2]);
        acc[3] = MFMA_(Al[1][q], Bh[1][q], acc[3]);
    }
    __builtin_amdgcn_s_setprio(0);
}

// 3-term product from the shared zero vector.
__device__ __forceinline__ void mm12(const u32x4 (&Ah)[2][4], const u32x4 (&Al)[2][4],
                                     const u32x4 (&Bh)[2][4], const u32x4 (&Bl)[2][4],
                                     const f32x16& Z0, f32x16 (&acc)[4]) {
    __builtin_amdgcn_s_setprio(1);
    acc[0] = MFMA_(Ah[0][0], Bh[0][0], Z0);
    acc[1] = MFMA_(Ah[0][0], Bh[1][0], Z0);
    acc[2] = MFMA_(Ah[1][0], Bh[0][0], Z0);
    acc[3] = MFMA_(Ah[1][0], Bh[1][0], Z0);
#pragma unroll
    for (int q = 1; q < 4; ++q) {
        acc[0] = MFMA_(Ah[0][q], Bh[0][q], acc[0]);
        acc[1] = MFMA_(Ah[0][q], Bh[1][q], acc[1]);
        acc[2] = MFMA_(Ah[1][q], Bh[0][q], acc[2]);
        acc[3] = MFMA_(Ah[1][q], Bh[1][q], acc[3]);
    }
#pragma unroll
    for (int q = 0; q < 4; ++q) {
        acc[0] = MFMA_(Ah[0][q], Bl[0][q], acc[0]);
        acc[1] = MFMA_(Ah[0][q], Bl[1][q], acc[1]);
        acc[2] = MFMA_(Ah[1][q], Bl[0][q], acc[2]);
        acc[3] = MFMA_(Ah[1][q], Bl[1][q], acc[3]);
    }
#pragma unroll
    for (int q = 0; q < 4; ++q) {
        acc[0] = MFMA_(Al[0][q], Bh[0][q], acc[0]);
        acc[1] = MFMA_(Al[0][q], Bh[1][q], acc[1]);
        acc[2] = MFMA_(Al[1][q], Bh[0][q], acc[2]);
        acc[3] = MFMA_(Al[1][q], Bh[1][q], acc[3]);
    }
    __builtin_amdgcn_s_setprio(0);
}

// C-layout acc tile (I,J) -> hi/lo A-frags (band J, q=2I+p). Verified r4-r9.
__device__ __forceinline__ void conv_tile(const f32x16& cc,
                                          u32x4& fh0, u32x4& fl0,
                                          u32x4& fh1, u32x4& fl1) {
#pragma unroll
    for (int p = 0; p < 2; ++p) {
        unsigned ah0, ah1, bh0, bh1, al0, al1, bl0, bl1;
        split2(cc[8*p+0], cc[8*p+1], ah0, al0);
        split2(cc[8*p+2], cc[8*p+3], ah1, al1);
        split2(cc[8*p+4], cc[8*p+5], bh0, bl0);
        split2(cc[8*p+6], cc[8*p+7], bh1, bl1);
        const u32x2 s0 = __builtin_amdgcn_permlane32_swap(ah0, bh0, false, false);
        const u32x2 s1 = __builtin_amdgcn_permlane32_swap(ah1, bh1, false, false);
        const u32x2 t0 = __builtin_amdgcn_permlane32_swap(al0, bl0, false, false);
        const u32x2 t1 = __builtin_amdgcn_permlane32_swap(al1, bl1, false, false);
        const u32x4 fh = {s0[0], s1[0], s0[1], s1[1]};
        const u32x4 fl = {t0[0], t1[0], t0[1], t1[1]};
        if (p == 0) { fh0 = fh; fl0 = fl; } else { fh1 = fh; fl1 = fl; }
    }
}
__device__ __forceinline__ void conv4(const f32x16 (&cc)[4],
                                      u32x4 (&FH)[2][4], u32x4 (&FL)[2][4]) {
    conv_tile(cc[0], FH[0][0], FL[0][0], FH[0][1], FL[0][1]);
    conv_tile(cc[1], FH[1][0], FL[1][0], FH[1][1], FL[1][1]);
    conv_tile(cc[2], FH[0][2], FL[0][2], FH[0][3], FL[0][3]);
    conv_tile(cc[3], FH[1][2], FL[1][2], FH[1][3], FL[1][3]);
}

__global__ __launch_bounds__(64, 2)
void spd_rectified_kernel(const float* __restrict__ Xg_all,
                          float* __restrict__ out_all) {
    // beta*Y0 hi/lo parking: lane-private 16B slots, conflict-free, 16 KB.
    __shared__ u32x4 park[16][64];

    // ---- anti-phase stagger: hashed 0..63 x ~64-cycle sleeps ----
    {
        const unsigned cnt = (blockIdx.x * 2654435761u) >> 26;
        for (unsigned i = 0; i < cnt; ++i) __builtin_amdgcn_s_sleep(1);
    }

    const int lane = threadIdx.x;       // 64 threads = 1 wave
    const int c    = lane & 31;
    const int hi   = lane >> 5;
    const int dv   = c - 4 * hi;        // diag: (r&3)+8*(r>>2) == dv

    const float* __restrict__ Xg = Xg_all + (size_t)blockIdx.x * 4096;
    float* __restrict__ Og = out_all + (size_t)blockIdx.x * 4096;

    // ---- load X in frag-shaped slices: row 32b+c, k = 16q+8hi+[0,8) ----
    float4 xv[2][4][2];
    float ss = 0.f;
#pragma unroll
    for (int b = 0; b < 2; ++b) {
        const float* xr = Xg + (32*b + c) * 64 + 8*hi;
#pragma unroll
        for (int q = 0; q < 4; ++q) {
            const float4 f0 = *reinterpret_cast<const float4*>(xr + 16*q);
            const float4 f1 = *reinterpret_cast<const float4*>(xr + 16*q + 4);
            xv[b][q][0] = f0; xv[b][q][1] = f1;
            ss += f0.x*f0.x + f0.y*f0.y + f0.z*f0.z + f0.w*f0.w;
            ss += f1.x*f1.x + f1.y*f1.y + f1.z*f1.z + f1.w*f1.w;
        }
    }
#pragma unroll
    for (int off = 32; off; off >>= 1) ss += __shfl_xor(ss, off, 64);
    const float fnorm = sqrtf(ss + 1e-30f);
    const float finv  = 1.0f / fnorm;

    // ---- spectral estimate: 6 power-iteration matvecs, lam = n6/n5 ----
    float v[4][8];
#pragma unroll
    for (int q = 0; q < 4; ++q)
#pragma unroll
        for (int j = 0; j < 8; ++j) v[q][j] = 1.0f;
    float n5 = 1.f, n6 = 1.f;
#pragma unroll
    for (int m = 1; m <= 6; ++m) {
        float y0 = 0.f, y1 = 0.f;
#pragma unroll
        for (int q = 0; q < 4; ++q) {
            const float4 a0 = xv[0][q][0], a1 = xv[0][q][1];
            const float4 b0 = xv[1][q][0], b1 = xv[1][q][1];
            y0 += a0.x*v[q][0] + a0.y*v[q][1] + a0.z*v[q][2] + a0.w*v[q][3]
                + a1.x*v[q][4] + a1.y*v[q][5] + a1.z*v[q][6] + a1.w*v[q][7];
            y1 += b0.x*v[q][0] + b0.y*v[q][1] + b0.z*v[q][2] + b0.w*v[q][3]
                + b1.x*v[q][4] + b1.y*v[q][5] + b1.z*v[q][6] + b1.w*v[q][7];
        }
        y0 += __shfl_xor(y0, 32, 64);
        y1 += __shfl_xor(y1, 32, 64);
        if (m == 3) { y0 *= finv; y1 *= finv; }   // overflow guard
        if (m >= 5) {
            float t = y0*y0 + y1*y1;
#pragma unroll
            for (int off = 16; off; off >>= 1) t += __shfl_xor(t, off, 64);
            if (m == 5) n5 = t; else n6 = t;
        }
        if (m < 6) {
#pragma unroll
            for (int q = 0; q < 4; ++q)
#pragma unroll
                for (int j = 0; j < 8; ++j)
                    v[q][j] = __shfl((q < 2) ? y0 : y1, 16*(q & 1) + 8*hi + j, 64);
        }
    }
    const float rho = sqrtf(n6 / n5);
    float nu = fminf(1.3f * rho, fnorm);
    if (!(nu > 1e-25f)) nu = fnorm;     // NaN/zero backstop -> Frobenius
    const float alpha = nu;
    const float ainvb = (1.0f / nu) * BETA;   // iterate stored as beta*Y

    const f32x16 Z0 = {};

    // ---- Ytil = beta*X/nu as hi/lo frags; park a copy ----
    u32x4 Yh[2][4], Yl[2][4], Gh[2][4], Gl[2][4];
#pragma unroll
    for (int b = 0; b < 2; ++b)
#pragma unroll
        for (int q = 0; q < 4; ++q) {
            const float4 f0 = xv[b][q][0], f1 = xv[b][q][1];
            unsigned h0, l0, h1, l1, h2, l2, h3, l3;
            split2(f0.x*ainvb, f0.y*ainvb, h0, l0);
            split2(f0.z*ainvb, f0.w*ainvb, h1, l1);
            split2(f1.x*ainvb, f1.y*ainvb, h2, l2);
            split2(f1.z*ainvb, f1.w*ainvb, h3, l3);
            Yh[b][q] = u32x4{h0, h1, h2, h3};
            Yl[b][q] = u32x4{l0, l1, l2, l3};
            park[b*4 + q][lane]     = Yh[b][q];
            park[8 + b*4 + q][lane] = Yl[b][q];
        }

    f32x16 za[4];

    // ---- 3 quintic iterations (beta-invariant, C0-seeded T-chain) ----
#pragma unroll 1
    for (int it = 0; it < 3; ++it) {
        mm12(Yh, Yl, Yh, Yl, Z0, za);                // za = beta^2*Y^2 = sqrt(QC)*Z
        conv4(za, Gh, Gl);                           // Z-frags (scaled)
#pragma unroll
        for (int r = 0; r < 16; ++r) {               // C0 = QA*I + (QB/sqrtQC)*za
            const int rwc = (r & 3) + 8*(r >> 2);
            za[0][r] = C0COEF*za[0][r] + ((rwc == dv) ? QA : 0.f);
            za[1][r] = C0COEF*za[1][r];
            za[2][r] = C0COEF*za[2][r];
            za[3][r] = C0COEF*za[3][r] + ((rwc == dv) ? QA : 0.f);
        }
        mm12c(Gh, Gl, Gh, Gl, za);                   // za = W = QA*I+QB*Z+QC*Z^2
        conv4(za, Gh, Gl);                           // W-frags
        mm12(Yh, Yl, Gh, Gl, Z0, za);                // za = beta*(Y*W) = Ytil_new
        conv4(za, Yh, Yl);
    }

    // ---- 3 cubic iterations; last one emits M = (I+S)/2 ----
#pragma unroll 1
    for (int it = 0; it < 3; ++it) {
        mm12(Yh, Yl, Yh, Yl, Z0, za);                // za = beta^2*Y^2
#pragma unroll
        for (int r = 0; r < 16; ++r) {               // W = 1.5I - 0.5*Y^2
            const int rwc = (r & 3) + 8*(r >> 2);
            za[0][r] = CWCOEF*za[0][r] + ((rwc == dv) ? 1.5f : 0.f);
            za[1][r] = CWCOEF*za[1][r];
            za[2][r] = CWCOEF*za[2][r];
            za[3][r] = CWCOEF*za[3][r] + ((rwc == dv) ? 1.5f : 0.f);
        }
        conv4(za, Gh, Gl);                           // W-frags
        mm12(Yh, Yl, Gh, Gl, Z0, za);                // za = beta*(Y*W)
        if (it == 2) {
#pragma unroll
            for (int r = 0; r < 16; ++r) {           // M = 0.5I + (0.5/beta)*za
                const int rwc = (r & 3) + 8*(r >> 2);
                za[0][r] = CMCOEF*za[0][r] + ((rwc == dv) ? 0.5f : 0.f);
                za[1][r] = CMCOEF*za[1][r];
                za[2][r] = CMCOEF*za[2][r];
                za[3][r] = CMCOEF*za[3][r] + ((rwc == dv) ? 0.5f : 0.f);
            }
        }
        conv4(za, Yh, Yl);                           // iterate / M frags
    }

    // ---- final: out = nu*Y0*M = (nu/beta)*(betaY0)*M ----
    u32x4 Ph[2][4], Pl[2][4];
#pragma unroll
    for (int b = 0; b < 2; ++b)
#pragma unroll
        for (int q = 0; q < 4; ++q) {
            Ph[b][q] = park[b*4 + q][lane];
            Pl[b][q] = park[8 + b*4 + q][lane];
        }
    mm12(Ph, Pl, Yh, Yl, Z0, za);                    // za = beta*Y0*M
    const float hscb = alpha * INVBETA;

#pragma unroll
    for (int t = 0; t < 4; ++t) {
        const int I = t >> 1, J = t & 1;
#pragma unroll
        for (int g = 0; g < 4; ++g)
#pragma unroll
            for (int j = 0; j < 4; ++j)
                Og[(32*I + 8*g + 4*hi + j) * 64 + 32*J + c] = hscb * za[t][4*g + j];
    }
}

extern "C" void kernel_launch(void* const* d_in, const int* in_sizes, int n_in,
                              void* d_out, int out_size, void* d_ws, size_t ws_size,
                              hipStream_t stream) {
    const float* x = (const float*)d_in[0];
    float* out = (float*)d_out;
    const int nmat = in_sizes[0] >> 12;
    spd_rectified_kernel<<<nmat, 64, 0, stream>>>(x, out);
}

// Round 11
// 379.906 us; speedup vs baseline: 1.0051x; 1.0051x over previous
//
#include <hip/hip_runtime.h>
#include <cstddef>

// SPDRectified: out = U clamp(S,eps) U^T for 16384 symmetric 64x64 fp32
// matrices via matrix-sign Newton-Schulz, one wave per matrix, bf16 matrix
// cores, 2-word hi/lo split (3-term products, fp32 accum).
//
// Round-10 = round-9 VERBATIM (378 us, absmax at the bf16-output floor) +
// pseudo-random per-block s_sleep stagger.
//   Evidence: r4 1-wave/SIMD MfmaUtil+VALUBusy = 45+55 = 100% (a lone wave
//   always keeps one pipe busy); r5 2-wave = 48+59 = 107% (second wave added
//   ~nothing) although m114 shows MFMA/VALU co-issue fine from different
//   waves. Diagnosis: identical streams launched together PHASE-LOCK --
//   both waves burst MFMA together (2x contention), then conv together.
//   Fix: hash(blockIdx)>>26 in [0,63] sleeps of ~64cyc = 0..4k cycle offset
//   (~ one product+conv period), pairing-agnostic. Mean cost ~2k cyc (~3%).
// Tripwires: absmax must stay exactly 0.03125; WRITE_SIZE == 262144 KB.
// Falsification: neutral dur => phase-lock theory dead (within-wave deps
// are the wall) -> next: 2-term products or roofline call.

#define QA 3.4445f
#define QB (-4.7750f)
#define QC 2.0315f
#define BETA    1.1938624f      // QC^(1/4)
#define C0COEF  (-3.3501551f)   // QB / sqrt(QC)
#define CWCOEF  (-0.3508013f)   // -0.5 / sqrt(QC)
#define CMCOEF  (0.4188090f)    // 0.5 / BETA
#define INVBETA (0.8376177f)    // 1 / BETA

using bf16x8 = __attribute__((ext_vector_type(8))) __bf16;
using f32x16 = __attribute__((ext_vector_type(16))) float;
using u32x4  = __attribute__((ext_vector_type(4))) unsigned int;
using u32x2  = __attribute__((ext_vector_type(2))) unsigned int;

__device__ __forceinline__ bf16x8 asbf(u32x4 v) { return __builtin_bit_cast(bf16x8, v); }

// Pack two f32 -> dword of 2 bf16 (RNE) + dword of 2 bf16 residuals.
__device__ __forceinline__ void split2(float x0, float x1, unsigned& h, unsigned& l) {
    unsigned hh, ll;
    asm("v_cvt_pk_bf16_f32 %0, %1, %2" : "=v"(hh) : "v"(x0), "v"(x1));
    const float e0 = x0 - __uint_as_float(hh << 16);
    const float e1 = x1 - __uint_as_float(hh & 0xFFFF0000u);
    asm("v_cvt_pk_bf16_f32 %0, %1, %2" : "=v"(ll) : "v"(e0), "v"(e1));
    h = hh; l = ll;
}

#define MFMA_(A, B, C) __builtin_amdgcn_mfma_f32_32x32x16_bf16(asbf(A), asbf(B), C, 0, 0, 0)

// 3-term product accumulating into pre-initialized acc (C-operand seeding).
__device__ __forceinline__ void mm12c(const u32x4 (&Ah)[2][4], const u32x4 (&Al)[2][4],
                                      const u32x4 (&Bh)[2][4], const u32x4 (&Bl)[2][4],
                                      f32x16 (&acc)[4]) {
    __builtin_amdgcn_s_setprio(1);
#pragma unroll
    for (int q = 0; q < 4; ++q) {
        acc[0] = MFMA_(Ah[0][q], Bh[0][q], acc[0]);
        acc[1] = MFMA_(Ah[0][q], Bh[1][q], acc[1]);
        acc[2] = MFMA_(Ah[1][q], Bh[0][q], acc[2]);
        acc[3] = MFMA_(Ah[1][q], Bh[1][q], acc[3]);
    }
#pragma unroll
    for (int q = 0; q < 4; ++q) {
        acc[0] = MFMA_(Ah[0][q], Bl[0][q], acc[0]);
        acc[1] = MFMA_(Ah[0][q], Bl[1][q], acc[1]);
        acc[2] = MFMA_(Ah[1][q], Bl[0][q], acc[2]);
        acc[3] = MFMA_(Ah[1][q], Bl[1][q], acc[3]);
    }
#pragma unroll
    for (int q = 0; q < 4; ++q) {
        acc[0] = MFMA_(Al[0][q], Bh[0][q], acc[0]);
        acc[1] = MFMA_(Al[0][q], Bh[1][q], acc[1]);
        acc[2] = MFMA_(Al[1][q], Bh[0][q], acc[2]);
        acc[3] = MFMA_(Al[1][q], Bh[1][q], acc[3]);
    }
    __builtin_amdgcn_s_setprio(0);
}

// 3-term product from the shared zero vector.
__device__ __forceinline__ void mm12(const u32x4 (&Ah)[2][4], const u32x4 (&Al)[2][4],
                                     const u32x4 (&Bh)[2][4], const u32x4 (&Bl)[2][4],
                                     const f32x16& Z0, f32x16 (&acc)[4]) {
    __builtin_amdgcn_s_setprio(1);
    acc[0] = MFMA_(Ah[0][0], Bh[0][0], Z0);
    acc[1] = MFMA_(Ah[0][0], Bh[1][0], Z0);
    acc[2] = MFMA_(Ah[1][0], Bh[0][0], Z0);
    acc[3] = MFMA_(Ah[1][0], Bh[1][0], Z0);
#pragma unroll
    for (int q = 1; q < 4; ++q) {
        acc[0] = MFMA_(Ah[0][q], Bh[0][q], acc[0]);
        acc[1] = MFMA_(Ah[0][q], Bh[1][q], acc[1]);
        acc[2] = MFMA_(Ah[1][q], Bh[0][q], acc[2]);
        acc[3] = MFMA_(Ah[1][q], Bh[1][q], acc[3]);
    }
#pragma unroll
    for (int q = 0; q < 4; ++q) {
        acc[0] = MFMA_(Ah[0][q], Bl[0][q], acc[0]);
        acc[1] = MFMA_(Ah[0][q], Bl[1][q], acc[1]);
        acc[2] = MFMA_(Ah[1][q], Bl[0][q], acc[2]);
        acc[3] = MFMA_(Ah[1][q], Bl[1][q], acc[3]);
    }
#pragma unroll
    for (int q = 0; q < 4; ++q) {
        acc[0] = MFMA_(Al[0][q], Bh[0][q], acc[0]);
        acc[1] = MFMA_(Al[0][q], Bh[1][q], acc[1]);
        acc[2] = MFMA_(Al[1][q], Bh[0][q], acc[2]);
        acc[3] = MFMA_(Al[1][q], Bh[1][q], acc[3]);
    }
    __builtin_amdgcn_s_setprio(0);
}

// C-layout acc tile (I,J) -> hi/lo A-frags (band J, q=2I+p). Verified r4-r9.
__device__ __forceinline__ void conv_tile(const f32x16& cc,
                                          u32x4& fh0, u32x4& fl0,
                                          u32x4& fh1, u32x4& fl1) {
#pragma unroll
    for (int p = 0; p < 2; ++p) {
        unsigned ah0, ah1, bh0, bh1, al0, al1, bl0, bl1;
        split2(cc[8*p+0], cc[8*p+1], ah0, al0);
        split2(cc[8*p+2], cc[8*p+3], ah1, al1);
        split2(cc[8*p+4], cc[8*p+5], bh0, bl0);
        split2(cc[8*p+6], cc[8*p+7], bh1, bl1);
        const u32x2 s0 = __builtin_amdgcn_permlane32_swap(ah0, bh0, false, false);
        const u32x2 s1 = __builtin_amdgcn_permlane32_swap(ah1, bh1, false, false);
        const u32x2 t0 = __builtin_amdgcn_permlane32_swap(al0, bl0, false, false);
        const u32x2 t1 = __builtin_amdgcn_permlane32_swap(al1, bl1, false, false);
        const u32x4 fh = {s0[0], s1[0], s0[1], s1[1]};
        const u32x4 fl = {t0[0], t1[0], t0[1], t1[1]};
        if (p == 0) { fh0 = fh; fl0 = fl; } else { fh1 = fh; fl1 = fl; }
    }
}
__device__ __forceinline__ void conv4(const f32x16 (&cc)[4],
                                      u32x4 (&FH)[2][4], u32x4 (&FL)[2][4]) {
    conv_tile(cc[0], FH[0][0], FL[0][0], FH[0][1], FL[0][1]);
    conv_tile(cc[1], FH[1][0], FL[1][0], FH[1][1], FL[1][1]);
    conv_tile(cc[2], FH[0][2], FL[0][2], FH[0][3], FL[0][3]);
    conv_tile(cc[3], FH[1][2], FL[1][2], FH[1][3], FL[1][3]);
}

__global__ __launch_bounds__(64, 2)
void spd_rectified_kernel(const float* __restrict__ Xg_all,
                          float* __restrict__ out_all) {
    // beta*Y0 hi/lo parking: lane-private 16B slots, conflict-free, 16 KB.
    __shared__ u32x4 park[16][64];

    // ---- anti-phase stagger: hashed 0..63 x ~64-cycle sleeps ----
    {
        const unsigned cnt = (blockIdx.x * 2654435761u) >> 26;
        for (unsigned i = 0; i < cnt; ++i) __builtin_amdgcn_s_sleep(1);
    }

    const int lane = threadIdx.x;       // 64 threads = 1 wave
    const int c    = lane & 31;
    const int hi   = lane >> 5;
    const int dv   = c - 4 * hi;        // diag: (r&3)+8*(r>>2) == dv

    const float* __restrict__ Xg = Xg_all + (size_t)blockIdx.x * 4096;
    float* __restrict__ Og = out_all + (size_t)blockIdx.x * 4096;

    // ---- load X in frag-shaped slices: row 32b+c, k = 16q+8hi+[0,8) ----
    float4 xv[2][4][2];
    float ss = 0.f;
#pragma unroll
    for (int b = 0; b < 2; ++b) {
        const float* xr = Xg + (32*b + c) * 64 + 8*hi;
#pragma unroll
        for (int q = 0; q < 4; ++q) {
            const float4 f0 = *reinterpret_cast<const float4*>(xr + 16*q);
            const float4 f1 = *reinterpret_cast<const float4*>(xr + 16*q + 4);
            xv[b][q][0] = f0; xv[b][q][1] = f1;
            ss += f0.x*f0.x + f0.y*f0.y + f0.z*f0.z + f0.w*f0.w;
            ss += f1.x*f1.x + f1.y*f1.y + f1.z*f1.z + f1.w*f1.w;
        }
    }
#pragma unroll
    for (int off = 32; off; off >>= 1) ss += __shfl_xor(ss, off, 64);
    const float fnorm = sqrtf(ss + 1e-30f);
    const float finv  = 1.0f / fnorm;

    // ---- spectral estimate: 6 power-iteration matvecs, lam = n6/n5 ----
    float v[4][8];
#pragma unroll
    for (int q = 0; q < 4; ++q)
#pragma unroll
        for (int j = 0; j < 8; ++j) v[q][j] = 1.0f;
    float n5 = 1.f, n6 = 1.f;
#pragma unroll
    for (int m = 1; m <= 6; ++m) {
        float y0 = 0.f, y1 = 0.f;
#pragma unroll
        for (int q = 0; q < 4; ++q) {
            const float4 a0 = xv[0][q][0], a1 = xv[0][q][1];
            const float4 b0 = xv[1][q][0], b1 = xv[1][q][1];
            y0 += a0.x*v[q][0] + a0.y*v[q][1] + a0.z*v[q][2] + a0.w*v[q][3]
                + a1.x*v[q][4] + a1.y*v[q][5] + a1.z*v[q][6] + a1.w*v[q][7];
            y1 += b0.x*v[q][0] + b0.y*v[q][1] + b0.z*v[q][2] + b0.w*v[q][3]
                + b1.x*v[q][4] + b1.y*v[q][5] + b1.z*v[q][6] + b1.w*v[q][7];
        }
        y0 += __shfl_xor(y0, 32, 64);
        y1 += __shfl_xor(y1, 32, 64);
        if (m == 3) { y0 *= finv; y1 *= finv; }   // overflow guard
        if (m >= 5) {
            float t = y0*y0 + y1*y1;
#pragma unroll
            for (int off = 16; off; off >>= 1) t += __shfl_xor(t, off, 64);
            if (m == 5) n5 = t; else n6 = t;
        }
        if (m < 6) {
#pragma unroll
            for (int q = 0; q < 4; ++q)
#pragma unroll
                for (int j = 0; j < 8; ++j)
                    v[q][j] = __shfl((q < 2) ? y0 : y1, 16*(q & 1) + 8*hi + j, 64);
        }
    }
    const float rho = sqrtf(n6 / n5);
    float nu = fminf(1.3f * rho, fnorm);
    if (!(nu > 1e-25f)) nu = fnorm;     // NaN/zero backstop -> Frobenius
    const float alpha = nu;
    const float ainvb = (1.0f / nu) * BETA;   // iterate stored as beta*Y

    const f32x16 Z0 = {};

    // ---- Ytil = beta*X/nu as hi/lo frags; park a copy ----
    u32x4 Yh[2][4], Yl[2][4], Gh[2][4], Gl[2][4];
#pragma unroll
    for (int b = 0; b < 2; ++b)
#pragma unroll
        for (int q = 0; q < 4; ++q) {
            const float4 f0 = xv[b][q][0], f1 = xv[b][q][1];
            unsigned h0, l0, h1, l1, h2, l2, h3, l3;
            split2(f0.x*ainvb, f0.y*ainvb, h0, l0);
            split2(f0.z*ainvb, f0.w*ainvb, h1, l1);
            split2(f1.x*ainvb, f1.y*ainvb, h2, l2);
            split2(f1.z*ainvb, f1.w*ainvb, h3, l3);
            Yh[b][q] = u32x4{h0, h1, h2, h3};
            Yl[b][q] = u32x4{l0, l1, l2, l3};
            park[b*4 + q][lane]     = Yh[b][q];
            park[8 + b*4 + q][lane] = Yl[b][q];
        }

    f32x16 za[4];

    // ---- 3 quintic iterations (beta-invariant, C0-seeded T-chain) ----
#pragma unroll 1
    for (int it = 0; it < 3; ++it) {
        mm12(Yh, Yl, Yh, Yl, Z0, za);                // za = beta^2*Y^2 = sqrt(QC)*Z
        conv4(za, Gh, Gl);                           // Z-frags (scaled)
#pragma unroll
        for (int r = 0; r < 16; ++r) {               // C0 = QA*I + (QB/sqrtQC)*za
            const int rwc = (r & 3) + 8*(r >> 2);
            za[0][r] = C0COEF*za[0][r] + ((rwc == dv) ? QA : 0.f);
            za[1][r] = C0COEF*za[1][r];
            za[2][r] = C0COEF*za[2][r];
            za[3][r] = C0COEF*za[3][r] + ((rwc == dv) ? QA : 0.f);
        }
        mm12c(Gh, Gl, Gh, Gl, za);                   // za = W = QA*I+QB*Z+QC*Z^2
        conv4(za, Gh, Gl);                           // W-frags
        mm12(Yh, Yl, Gh, Gl, Z0, za);                // za = beta*(Y*W) = Ytil_new
        conv4(za, Yh, Yl);
    }

    // ---- 3 cubic iterations; last one emits M = (I+S)/2 ----
#pragma unroll 1
    for (int it = 0; it < 3; ++it) {
        mm12(Yh, Yl, Yh, Yl, Z0, za);                // za = beta^2*Y^2
#pragma unroll
        for (int r = 0; r < 16; ++r) {               // W = 1.5I - 0.5*Y^2
            const int rwc = (r & 3) + 8*(r >> 2);
            za[0][r] = CWCOEF*za[0][r] + ((rwc == dv) ? 1.5f : 0.f);
            za[1][r] = CWCOEF*za[1][r];
            za[2][r] = CWCOEF*za[2][r];
            za[3][r] = CWCOEF*za[3][r] + ((rwc == dv) ? 1.5f : 0.f);
        }
        conv4(za, Gh, Gl);                           // W-frags
        mm12(Yh, Yl, Gh, Gl, Z0, za);                // za = beta*(Y*W)
        if (it == 2) {
#pragma unroll
            for (int r = 0; r < 16; ++r) {           // M = 0.5I + (0.5/beta)*za
                const int rwc = (r & 3) + 8*(r >> 2);
                za[0][r] = CMCOEF*za[0][r] + ((rwc == dv) ? 0.5f : 0.f);
                za[1][r] = CMCOEF*za[1][r];
                za[2][r] = CMCOEF*za[2][r];
                za[3][r] = CMCOEF*za[3][r] + ((rwc == dv) ? 0.5f : 0.f);
            }
        }
        conv4(za, Yh, Yl);                           // iterate / M frags
    }

    // ---- final: out = nu*Y0*M = (nu/beta)*(betaY0)*M ----
    u32x4 Ph[2][4], Pl[2][4];
#pragma unroll
    for (int b = 0; b < 2; ++b)
#pragma unroll
        for (int q = 0; q < 4; ++q) {
            Ph[b][q] = park[b*4 + q][lane];
            Pl[b][q] = park[8 + b*4 + q][lane];
        }
    mm12(Ph, Pl, Yh, Yl, Z0, za);                    // za = beta*Y0*M
    const float hscb = alpha * INVBETA;

#pragma unroll
    for (int t = 0; t < 4; ++t) {
        const int I = t >> 1, J = t & 1;
#pragma unroll
        for (int g = 0; g < 4; ++g)
#pragma unroll
            for (int j = 0; j < 4; ++j)
                Og[(32*I + 8*g + 4*hi + j) * 64 + 32*J + c] = hscb * za[t][4*g + j];
    }
}

extern "C" void kernel_launch(void* const* d_in, const int* in_sizes, int n_in,
                              void* d_out, int out_size, void* d_ws, size_t ws_size,
                              hipStream_t stream) {
    const float* x = (const float*)d_in[0];
    float* out = (float*)d_out;
    const int nmat = in_sizes[0] >> 12;
    spd_rectified_kernel<<<nmat, 64, 0, stream>>>(x, out);
}

// Round 12
// 339.623 us; speedup vs baseline: 1.1243x; 1.1186x over previous
//
#include <hip/hip_runtime.h>
#include <cstddef>

// SPDRectified: out = U clamp(S,eps) U^T for 16384 symmetric 64x64 fp32
// matrices via matrix-sign Newton-Schulz, one wave per matrix, bf16 matrix
// cores, hi/lo split, fp32 accum. Spectral normalization (r9).
//
// Round-12 = round-9 minus the (proven-neutral) stagger, plus CUBIC-LITE:
//   Precision is phase-dependent. Quintics amplify noise (P' up to 6.5 near
//   the 1.264 trap edge; r6/r8 1-term experiments escaped) -> keep 3-term.
//   Cubics contract noise (f'(1)=0, |f|<=1 on |x|<=sqrt3 -> NaN impossible)
//   -> 2-block products A*B ~ Ah*Bh + Al*Bh (B's lo unused):
//     error ~2^-8 spectral/product; cubic-1/2 contributions contracted
//     quadratically; cubic-3's ~8e-3 -> out err ~ nu*8e-3/2 ~ 0.046.
//   Cubic products 48->32 MFMA (total 768->672) and W gets hi-only conv.
// Tripwires: absmax expected 0.05-0.07, MUST be < 0.119 (else revert
// cubics to 3-term); WRITE_SIZE == 262144 KB exactly (spill tripwire).

#define QA 3.4445f
#define QB (-4.7750f)
#define QC 2.0315f
#define BETA    1.1938624f      // QC^(1/4)
#define C0COEF  (-3.3501551f)   // QB / sqrt(QC)
#define CWCOEF  (-0.3508013f)   // -0.5 / sqrt(QC)
#define CMCOEF  (0.4188090f)    // 0.5 / BETA
#define INVBETA (0.8376177f)    // 1 / BETA

using bf16x8 = __attribute__((ext_vector_type(8))) __bf16;
using f32x16 = __attribute__((ext_vector_type(16))) float;
using u32x4  = __attribute__((ext_vector_type(4))) unsigned int;
using u32x2  = __attribute__((ext_vector_type(2))) unsigned int;

__device__ __forceinline__ bf16x8 asbf(u32x4 v) { return __builtin_bit_cast(bf16x8, v); }

// Pack two f32 -> dword of 2 bf16 (RNE) + dword of 2 bf16 residuals.
__device__ __forceinline__ void split2(float x0, float x1, unsigned& h, unsigned& l) {
    unsigned hh, ll;
    asm("v_cvt_pk_bf16_f32 %0, %1, %2" : "=v"(hh) : "v"(x0), "v"(x1));
    const float e0 = x0 - __uint_as_float(hh << 16);
    const float e1 = x1 - __uint_as_float(hh & 0xFFFF0000u);
    asm("v_cvt_pk_bf16_f32 %0, %1, %2" : "=v"(ll) : "v"(e0), "v"(e1));
    h = hh; l = ll;
}
__device__ __forceinline__ unsigned cvtpk(float x0, float x1) {
    unsigned hh;
    asm("v_cvt_pk_bf16_f32 %0, %1, %2" : "=v"(hh) : "v"(x0), "v"(x1));
    return hh;
}

#define MFMA_(A, B, C) __builtin_amdgcn_mfma_f32_32x32x16_bf16(asbf(A), asbf(B), C, 0, 0, 0)

// 3-term product accumulating into pre-initialized acc (C-operand seeding).
__device__ __forceinline__ void mm12c(const u32x4 (&Ah)[2][4], const u32x4 (&Al)[2][4],
                                      const u32x4 (&Bh)[2][4], const u32x4 (&Bl)[2][4],
                                      f32x16 (&acc)[4]) {
    __builtin_amdgcn_s_setprio(1);
#pragma unroll
    for (int q = 0; q < 4; ++q) {
        acc[0] = MFMA_(Ah[0][q], Bh[0][q], acc[0]);
        acc[1] = MFMA_(Ah[0][q], Bh[1][q], acc[1]);
        acc[2] = MFMA_(Ah[1][q], Bh[0][q], acc[2]);
        acc[3] = MFMA_(Ah[1][q], Bh[1][q], acc[3]);
    }
#pragma unroll
    for (int q = 0; q < 4; ++q) {
        acc[0] = MFMA_(Ah[0][q], Bl[0][q], acc[0]);
        acc[1] = MFMA_(Ah[0][q], Bl[1][q], acc[1]);
        acc[2] = MFMA_(Ah[1][q], Bl[0][q], acc[2]);
        acc[3] = MFMA_(Ah[1][q], Bl[1][q], acc[3]);
    }
#pragma unroll
    for (int q = 0; q < 4; ++q) {
        acc[0] = MFMA_(Al[0][q], Bh[0][q], acc[0]);
        acc[1] = MFMA_(Al[0][q], Bh[1][q], acc[1]);
        acc[2] = MFMA_(Al[1][q], Bh[0][q], acc[2]);
        acc[3] = MFMA_(Al[1][q], Bh[1][q], acc[3]);
    }
    __builtin_amdgcn_s_setprio(0);
}

// 3-term product from the shared zero vector.
__device__ __forceinline__ void mm12(const u32x4 (&Ah)[2][4], const u32x4 (&Al)[2][4],
                                     const u32x4 (&Bh)[2][4], const u32x4 (&Bl)[2][4],
                                     const f32x16& Z0, f32x16 (&acc)[4]) {
    __builtin_amdgcn_s_setprio(1);
    acc[0] = MFMA_(Ah[0][0], Bh[0][0], Z0);
    acc[1] = MFMA_(Ah[0][0], Bh[1][0], Z0);
    acc[2] = MFMA_(Ah[1][0], Bh[0][0], Z0);
    acc[3] = MFMA_(Ah[1][0], Bh[1][0], Z0);
#pragma unroll
    for (int q = 1; q < 4; ++q) {
        acc[0] = MFMA_(Ah[0][q], Bh[0][q], acc[0]);
        acc[1] = MFMA_(Ah[0][q], Bh[1][q], acc[1]);
        acc[2] = MFMA_(Ah[1][q], Bh[0][q], acc[2]);
        acc[3] = MFMA_(Ah[1][q], Bh[1][q], acc[3]);
    }
#pragma unroll
    for (int q = 0; q < 4; ++q) {
        acc[0] = MFMA_(Ah[0][q], Bl[0][q], acc[0]);
        acc[1] = MFMA_(Ah[0][q], Bl[1][q], acc[1]);
        acc[2] = MFMA_(Ah[1][q], Bl[0][q], acc[2]);
        acc[3] = MFMA_(Ah[1][q], Bl[1][q], acc[3]);
    }
#pragma unroll
    for (int q = 0; q < 4; ++q) {
        acc[0] = MFMA_(Al[0][q], Bh[0][q], acc[0]);
        acc[1] = MFMA_(Al[0][q], Bh[1][q], acc[1]);
        acc[2] = MFMA_(Al[1][q], Bh[0][q], acc[2]);
        acc[3] = MFMA_(Al[1][q], Bh[1][q], acc[3]);
    }
    __builtin_amdgcn_s_setprio(0);
}

// 2-block product (cubic-lite): acc = (Ah+Al)*Bh -- B's lo never used.
__device__ __forceinline__ void mm2b(const u32x4 (&Ah)[2][4], const u32x4 (&Al)[2][4],
                                     const u32x4 (&Bh)[2][4],
                                     const f32x16& Z0, f32x16 (&acc)[4]) {
    __builtin_amdgcn_s_setprio(1);
    acc[0] = MFMA_(Ah[0][0], Bh[0][0], Z0);
    acc[1] = MFMA_(Ah[0][0], Bh[1][0], Z0);
    acc[2] = MFMA_(Ah[1][0], Bh[0][0], Z0);
    acc[3] = MFMA_(Ah[1][0], Bh[1][0], Z0);
#pragma unroll
    for (int q = 1; q < 4; ++q) {
        acc[0] = MFMA_(Ah[0][q], Bh[0][q], acc[0]);
        acc[1] = MFMA_(Ah[0][q], Bh[1][q], acc[1]);
        acc[2] = MFMA_(Ah[1][q], Bh[0][q], acc[2]);
        acc[3] = MFMA_(Ah[1][q], Bh[1][q], acc[3]);
    }
#pragma unroll
    for (int q = 0; q < 4; ++q) {
        acc[0] = MFMA_(Al[0][q], Bh[0][q], acc[0]);
        acc[1] = MFMA_(Al[0][q], Bh[1][q], acc[1]);
        acc[2] = MFMA_(Al[1][q], Bh[0][q], acc[2]);
        acc[3] = MFMA_(Al[1][q], Bh[1][q], acc[3]);
    }
    __builtin_amdgcn_s_setprio(0);
}

// C-layout acc tile (I,J) -> hi/lo A-frags (band J, q=2I+p). Verified r4-r9.
__device__ __forceinline__ void conv_tile(const f32x16& cc,
                                          u32x4& fh0, u32x4& fl0,
                                          u32x4& fh1, u32x4& fl1) {
#pragma unroll
    for (int p = 0; p < 2; ++p) {
        unsigned ah0, ah1, bh0, bh1, al0, al1, bl0, bl1;
        split2(cc[8*p+0], cc[8*p+1], ah0, al0);
        split2(cc[8*p+2], cc[8*p+3], ah1, al1);
        split2(cc[8*p+4], cc[8*p+5], bh0, bl0);
        split2(cc[8*p+6], cc[8*p+7], bh1, bl1);
        const u32x2 s0 = __builtin_amdgcn_permlane32_swap(ah0, bh0, false, false);
        const u32x2 s1 = __builtin_amdgcn_permlane32_swap(ah1, bh1, false, false);
        const u32x2 t0 = __builtin_amdgcn_permlane32_swap(al0, bl0, false, false);
        const u32x2 t1 = __builtin_amdgcn_permlane32_swap(al1, bl1, false, false);
        const u32x4 fh = {s0[0], s1[0], s0[1], s1[1]};
        const u32x4 fl = {t0[0], t1[0], t0[1], t1[1]};
        if (p == 0) { fh0 = fh; fl0 = fl; } else { fh1 = fh; fl1 = fl; }
    }
}
__device__ __forceinline__ void conv4(const f32x16 (&cc)[4],
                                      u32x4 (&FH)[2][4], u32x4 (&FL)[2][4]) {
    conv_tile(cc[0], FH[0][0], FL[0][0], FH[0][1], FL[0][1]);
    conv_tile(cc[1], FH[1][0], FL[1][0], FH[1][1], FL[1][1]);
    conv_tile(cc[2], FH[0][2], FL[0][2], FH[0][3], FL[0][3]);
    conv_tile(cc[3], FH[1][2], FL[1][2], FH[1][3], FL[1][3]);
}

// hi-only conv (for cubic W, whose lo is never consumed). Same byte mapping.
__device__ __forceinline__ void conv1_tile(const f32x16& cc, u32x4& fh0, u32x4& fh1) {
#pragma unroll
    for (int p = 0; p < 2; ++p) {
        const unsigned a0 = cvtpk(cc[8*p+0], cc[8*p+1]);
        const unsigned a1 = cvtpk(cc[8*p+2], cc[8*p+3]);
        const unsigned b0 = cvtpk(cc[8*p+4], cc[8*p+5]);
        const unsigned b1 = cvtpk(cc[8*p+6], cc[8*p+7]);
        const u32x2 s0 = __builtin_amdgcn_permlane32_swap(a0, b0, false, false);
        const u32x2 s1 = __builtin_amdgcn_permlane32_swap(a1, b1, false, false);
        const u32x4 fh = {s0[0], s1[0], s0[1], s1[1]};
        if (p == 0) fh0 = fh; else fh1 = fh;
    }
}
__device__ __forceinline__ void conv1x4(const f32x16 (&cc)[4], u32x4 (&FH)[2][4]) {
    conv1_tile(cc[0], FH[0][0], FH[0][1]);
    conv1_tile(cc[1], FH[1][0], FH[1][1]);
    conv1_tile(cc[2], FH[0][2], FH[0][3]);
    conv1_tile(cc[3], FH[1][2], FH[1][3]);
}

__global__ __launch_bounds__(64, 2)
void spd_rectified_kernel(const float* __restrict__ Xg_all,
                          float* __restrict__ out_all) {
    // beta*Y0 hi/lo parking: lane-private 16B slots, conflict-free, 16 KB.
    __shared__ u32x4 park[16][64];

    const int lane = threadIdx.x;       // 64 threads = 1 wave
    const int c    = lane & 31;
    const int hi   = lane >> 5;
    const int dv   = c - 4 * hi;        // diag: (r&3)+8*(r>>2) == dv

    const float* __restrict__ Xg = Xg_all + (size_t)blockIdx.x * 4096;
    float* __restrict__ Og = out_all + (size_t)blockIdx.x * 4096;

    // ---- load X in frag-shaped slices: row 32b+c, k = 16q+8hi+[0,8) ----
    float4 xv[2][4][2];
    float ss = 0.f;
#pragma unroll
    for (int b = 0; b < 2; ++b) {
        const float* xr = Xg + (32*b + c) * 64 + 8*hi;
#pragma unroll
        for (int q = 0; q < 4; ++q) {
            const float4 f0 = *reinterpret_cast<const float4*>(xr + 16*q);
            const float4 f1 = *reinterpret_cast<const float4*>(xr + 16*q + 4);
            xv[b][q][0] = f0; xv[b][q][1] = f1;
            ss += f0.x*f0.x + f0.y*f0.y + f0.z*f0.z + f0.w*f0.w;
            ss += f1.x*f1.x + f1.y*f1.y + f1.z*f1.z + f1.w*f1.w;
        }
    }
#pragma unroll
    for (int off = 32; off; off >>= 1) ss += __shfl_xor(ss, off, 64);
    const float fnorm = sqrtf(ss + 1e-30f);
    const float finv  = 1.0f / fnorm;

    // ---- spectral estimate: 6 power-iteration matvecs, lam = n6/n5 ----
    float v[4][8];
#pragma unroll
    for (int q = 0; q < 4; ++q)
#pragma unroll
        for (int j = 0; j < 8; ++j) v[q][j] = 1.0f;
    float n5 = 1.f, n6 = 1.f;
#pragma unroll
    for (int m = 1; m <= 6; ++m) {
        float y0 = 0.f, y1 = 0.f;
#pragma unroll
        for (int q = 0; q < 4; ++q) {
            const float4 a0 = xv[0][q][0], a1 = xv[0][q][1];
            const float4 b0 = xv[1][q][0], b1 = xv[1][q][1];
            y0 += a0.x*v[q][0] + a0.y*v[q][1] + a0.z*v[q][2] + a0.w*v[q][3]
                + a1.x*v[q][4] + a1.y*v[q][5] + a1.z*v[q][6] + a1.w*v[q][7];
            y1 += b0.x*v[q][0] + b0.y*v[q][1] + b0.z*v[q][2] + b0.w*v[q][3]
                + b1.x*v[q][4] + b1.y*v[q][5] + b1.z*v[q][6] + b1.w*v[q][7];
        }
        y0 += __shfl_xor(y0, 32, 64);
        y1 += __shfl_xor(y1, 32, 64);
        if (m == 3) { y0 *= finv; y1 *= finv; }   // overflow guard
        if (m >= 5) {
            float t = y0*y0 + y1*y1;
#pragma unroll
            for (int off = 16; off; off >>= 1) t += __shfl_xor(t, off, 64);
            if (m == 5) n5 = t; else n6 = t;
        }
        if (m < 6) {
#pragma unroll
            for (int q = 0; q < 4; ++q)
#pragma unroll
                for (int j = 0; j < 8; ++j)
                    v[q][j] = __shfl((q < 2) ? y0 : y1, 16*(q & 1) + 8*hi + j, 64);
        }
    }
    const float rho = sqrtf(n6 / n5);
    float nu = fminf(1.3f * rho, fnorm);
    if (!(nu > 1e-25f)) nu = fnorm;     // NaN/zero backstop -> Frobenius
    const float alpha = nu;
    const float ainvb = (1.0f / nu) * BETA;   // iterate stored as beta*Y

    const f32x16 Z0 = {};

    // ---- Ytil = beta*X/nu as hi/lo frags; park a copy ----
    u32x4 Yh[2][4], Yl[2][4], Gh[2][4], Gl[2][4];
#pragma unroll
    for (int b = 0; b < 2; ++b)
#pragma unroll
        for (int q = 0; q < 4; ++q) {
            const float4 f0 = xv[b][q][0], f1 = xv[b][q][1];
            unsigned h0, l0, h1, l1, h2, l2, h3, l3;
            split2(f0.x*ainvb, f0.y*ainvb, h0, l0);
            split2(f0.z*ainvb, f0.w*ainvb, h1, l1);
            split2(f1.x*ainvb, f1.y*ainvb, h2, l2);
            split2(f1.z*ainvb, f1.w*ainvb, h3, l3);
            Yh[b][q] = u32x4{h0, h1, h2, h3};
            Yl[b][q] = u32x4{l0, l1, l2, l3};
            park[b*4 + q][lane]     = Yh[b][q];
            park[8 + b*4 + q][lane] = Yl[b][q];
        }

    f32x16 za[4];

    // ---- 3 quintic iterations (3-term; beta-invariant C0-seeded T-chain) ----
#pragma unroll 1
    for (int it = 0; it < 3; ++it) {
        mm12(Yh, Yl, Yh, Yl, Z0, za);                // za = beta^2*Y^2 = sqrt(QC)*Z
        conv4(za, Gh, Gl);                           // Z-frags (scaled)
#pragma unroll
        for (int r = 0; r < 16; ++r) {               // C0 = QA*I + (QB/sqrtQC)*za
            const int rwc = (r & 3) + 8*(r >> 2);
            za[0][r] = C0COEF*za[0][r] + ((rwc == dv) ? QA : 0.f);
            za[1][r] = C0COEF*za[1][r];
            za[2][r] = C0COEF*za[2][r];
            za[3][r] = C0COEF*za[3][r] + ((rwc == dv) ? QA : 0.f);
        }
        mm12c(Gh, Gl, Gh, Gl, za);                   // za = W = QA*I+QB*Z+QC*Z^2
        conv4(za, Gh, Gl);                           // W-frags
        mm12(Yh, Yl, Gh, Gl, Z0, za);                // za = beta*(Y*W) = Ytil_new
        conv4(za, Yh, Yl);
    }

    // ---- 3 cubic iterations (2-block lite); last emits M = (I+S)/2 ----
#pragma unroll 1
    for (int it = 0; it < 3; ++it) {
        mm2b(Yh, Yl, Yh, Z0, za);                    // za ~ beta^2*Y^2 (2-block)
#pragma unroll
        for (int r = 0; r < 16; ++r) {               // W = 1.5I - 0.5*Y^2
            const int rwc = (r & 3) + 8*(r >> 2);
            za[0][r] = CWCOEF*za[0][r] + ((rwc == dv) ? 1.5f : 0.f);
            za[1][r] = CWCOEF*za[1][r];
            za[2][r] = CWCOEF*za[2][r];
            za[3][r] = CWCOEF*za[3][r] + ((rwc == dv) ? 1.5f : 0.f);
        }
        conv1x4(za, Gh);                             // W hi-frags only
        mm2b(Yh, Yl, Gh, Z0, za);                    // za = beta*(Y*W) (2-block)
        if (it == 2) {
#pragma unroll
            for (int r = 0; r < 16; ++r) {           // M = 0.5I + (0.5/beta)*za
                const int rwc = (r & 3) + 8*(r >> 2);
                za[0][r] = CMCOEF*za[0][r] + ((rwc == dv) ? 0.5f : 0.f);
                za[1][r] = CMCOEF*za[1][r];
                za[2][r] = CMCOEF*za[2][r];
                za[3][r] = CMCOEF*za[3][r] + ((rwc == dv) ? 0.5f : 0.f);
            }
        }
        conv4(za, Yh, Yl);                           // iterate / M frags (hi/lo)
    }

    // ---- final: out = nu*Y0*M = (nu/beta)*(betaY0)*M, 3-term ----
    u32x4 Ph[2][4], Pl[2][4];
#pragma unroll
    for (int b = 0; b < 2; ++b)
#pragma unroll
        for (int q = 0; q < 4; ++q) {
            Ph[b][q] = park[b*4 + q][lane];
            Pl[b][q] = park[8 + b*4 + q][lane];
        }
    mm12(Ph, Pl, Yh, Yl, Z0, za);                    // za = beta*Y0*M
    const float hscb = alpha * INVBETA;

#pragma unroll
    for (int t = 0; t < 4; ++t) {
        const int I = t >> 1, J = t & 1;
#pragma unroll
        for (int g = 0; g < 4; ++g)
#pragma unroll
            for (int j = 0; j < 4; ++j)
                Og[(32*I + 8*g + 4*hi + j) * 64 + 32*J + c] = hscb * za[t][4*g + j];
    }
}

extern "C" void kernel_launch(void* const* d_in, const int* in_sizes, int n_in,
                              void* d_out, int out_size, void* d_ws, size_t ws_size,
                              hipStream_t stream) {
    const float* x = (const float*)d_in[0];
    float* out = (float*)d_out;
    const int nmat = in_sizes[0] >> 12;
    spd_rectified_kernel<<<nmat, 64, 0, stream>>>(x, out);
}